// Round 3
// baseline (550.424 us; speedup 1.0000x reference)
//
#include <hip/hip_runtime.h>
#include <math.h>

// ---------------------------------------------------------------------------
// EDANet fused inference kernel, MI355X (gfx950).  Round 3.
// All GEMM-shaped stages via mfma_f32_16x16x32_bf16 (fp32 accum); per-row
// scalar math (attention/entropy/tau/LN/gelu) on VALU.
// Round-3 change: occupancy. 32 rows/block (LDS 33.8KB -> 4 blocks/CU),
// params read straight from global (uniform -> s_load; per-col -> L1),
// __launch_bounds__(256,4) to cap VGPR at 128 (16 waves/CU target).
// ---------------------------------------------------------------------------

typedef unsigned short u16;
typedef __attribute__((ext_vector_type(8))) short short8;
typedef __attribute__((ext_vector_type(4))) short short4v;
typedef __attribute__((ext_vector_type(4))) float f32x4;

struct Ptrs { const float* p[51]; };

__device__ __host__ __forceinline__ u16 f2bf(float f) {
  union { float f; unsigned int i; } v; v.f = f;
  unsigned int u = v.i;
  unsigned int r = (u + 0x7fffu + ((u >> 16) & 1u)) >> 16;  // RNE
  return (u16)r;
}
__device__ __forceinline__ float bf2f(u16 u) {
  union { unsigned int i; float f; } v; v.i = ((unsigned int)u) << 16; return v.f;
}
__device__ __forceinline__ float gelu_exact(float y) {
  return 0.5f * y * (1.f + erff(y * 0.70710678118654752f));
}
__device__ __forceinline__ float sigmoidf_(float y) {
  return 1.f / (1.f + expf(-y));
}

// ---- workspace layout --------------------------------------------------
#define QWT_O   0         // [128][256]
#define FPT_O   32768     // [256][128]
#define SE1T_O  65536     // [64][256]
#define SE2T_O  81920     // [256][64]
#define B1T_O   98304     // [256][256]
#define B2T_O   163840    // [128][256]
#define R2T_O   196608    // [128][256]
#define B3T_O   229376    // [64][128]
#define R3T_O   237568    // [64][128]
#define C1T_O   245760    // [32][64]
#define W_TOTAL 247808
#define WSP_F_OFF 123904
// param blob float offsets
#define BN0S_P 0
#define BN0T_P 256
#define PK_P   512
#define PV_P   1536
#define OW_P   2560
#define TW1_P  6656
#define TB1_P  6784
#define TW2_P  6912
#define TB2_P  7040
#define OB_P   7044
#define LNG_P  7172
#define LNB_P  7300
#define QB_P   7428
#define FPB_P  7556
#define FLNG_P 7812
#define FLNB_P 8068
#define SEB1_P 8324
#define SEB2_P 8388
#define B1S_P  8644
#define B1TT_P 8900
#define B2S_P  9156
#define B2TT_P 9284
#define R2B_P  9412
#define B3S_P  9540
#define B3TT_P 9604
#define R3B_P  9668
#define C1B_P  9732
#define C2W_P  9764
#define C2B_P  9796
#define P_TOTAL 9797

#define XSTRIDE 264   // 256 + 8 bf16 pad (row stride 528B)
#define ROWS 32

// ---- prep: transpose weights to bf16 [out][in] -------------------------
__global__ void prep_weights(Ptrs P, u16* __restrict__ w) {
  for (int idx = blockIdx.x * blockDim.x + threadIdx.x; idx < W_TOTAL;
       idx += gridDim.x * blockDim.x) {
    int i = idx; float v;
    if (i < 32768)       { int n = i >> 8, k = i & 255; v = P.p[5][(n >> 5) * 8192 + k * 32 + (n & 31)]; }
    else if (i < 65536)  { i -= 32768;  int n = i >> 7, k = i & 127; v = P.p[17][k * 256 + n]; }
    else if (i < 81920)  { i -= 65536;  int n = i >> 8, k = i & 255; v = P.p[21][k * 64 + n]; }
    else if (i < 98304)  { i -= 81920;  int n = i >> 6, k = i & 63;  v = P.p[23][k * 256 + n]; }
    else if (i < 163840) { i -= 98304;  int n = i >> 8, k = i & 255; v = P.p[25][k * 256 + n]; }
    else if (i < 196608) { i -= 163840; int n = i >> 8, k = i & 255; v = P.p[31][k * 128 + n]; }
    else if (i < 229376) { i -= 196608; int n = i >> 8, k = i & 255; v = P.p[37][k * 128 + n]; }
    else if (i < 237568) { i -= 229376; int n = i >> 7, k = i & 127; v = P.p[39][k * 64 + n]; }
    else if (i < 245760) { i -= 237568; int n = i >> 7, k = i & 127; v = P.p[45][k * 64 + n]; }
    else                 { i -= 245760; int n = i >> 6, k = i & 63;  v = P.p[47][k * 32 + n]; }
    w[idx] = f2bf(v);
  }
}

// ---- prep: fp32 params (BN folded to scale/bias) -----------------------
__global__ void prep_params(Ptrs P, float* __restrict__ wp) {
  int idx = blockIdx.x * blockDim.x + threadIdx.x;
  if (idx >= P_TOTAL) return;
  const float eps = 1e-5f;
  int i = idx; float v;
  if (i < 256)        { v = P.p[1][i] * rsqrtf(P.p[4][i] + eps); }
  else if (i < 512)   { int c = i - 256; float s = P.p[1][c] * rsqrtf(P.p[4][c] + eps); v = P.p[2][c] - P.p[3][c] * s; }
  else if (i < 1536)  v = P.p[7][i - 512];
  else if (i < 2560)  v = P.p[8][i - 1536];
  else if (i < 6656)  v = P.p[13][i - 2560];
  else if (i < 6784)  v = P.p[9][i - 6656];
  else if (i < 6912)  v = P.p[10][i - 6784];
  else if (i < 7040)  v = P.p[11][i - 6912];
  else if (i < 7044)  v = P.p[12][i - 7040];
  else if (i < 7172)  v = P.p[14][i - 7044];
  else if (i < 7300)  v = P.p[15][i - 7172];
  else if (i < 7428)  v = P.p[16][i - 7300];
  else if (i < 7556)  v = P.p[6][i - 7428];
  else if (i < 7812)  v = P.p[18][i - 7556];
  else if (i < 8068)  v = P.p[19][i - 7812];
  else if (i < 8324)  v = P.p[20][i - 8068];
  else if (i < 8388)  v = P.p[22][i - 8324];
  else if (i < 8644)  v = P.p[24][i - 8388];
  else if (i < 8900)  { int c = i - 8644; v = P.p[27][c] * rsqrtf(P.p[30][c] + eps); }
  else if (i < 9156)  { int c = i - 8900; float s = P.p[27][c] * rsqrtf(P.p[30][c] + eps); v = P.p[28][c] + (P.p[26][c] - P.p[29][c]) * s; }
  else if (i < 9284)  { int c = i - 9156; v = P.p[33][c] * rsqrtf(P.p[36][c] + eps); }
  else if (i < 9412)  { int c = i - 9284; float s = P.p[33][c] * rsqrtf(P.p[36][c] + eps); v = P.p[34][c] + (P.p[32][c] - P.p[35][c]) * s; }
  else if (i < 9540)  v = P.p[38][i - 9412];
  else if (i < 9604)  { int c = i - 9540; v = P.p[41][c] * rsqrtf(P.p[44][c] + eps); }
  else if (i < 9668)  { int c = i - 9604; float s = P.p[41][c] * rsqrtf(P.p[44][c] + eps); v = P.p[42][c] + (P.p[40][c] - P.p[43][c]) * s; }
  else if (i < 9732)  v = P.p[46][i - 9668];
  else if (i < 9764)  v = P.p[48][i - 9732];
  else if (i < 9796)  v = P.p[49][i - 9764];
  else                v = P.p[50][0];
  wp[idx] = v;
}

// ---- wave-level GEMM tile: 32 rows x (NT*16) cols, K from LDS ----------
// A-frag: lane reads row (m*16 + lane&15), k = kc*32 + (lane>>4)*8 .. +8
// B-frag: lane reads WT row (n0 + nt*16 + lane&15), same k pattern.
template<int K, int NT>
__device__ __forceinline__ void gemm_tile(const u16* A, const u16* __restrict__ WT,
                                          int n0, int kg, int l15, f32x4 acc[2][NT]) {
#pragma unroll
  for (int kc = 0; kc < K / 32; ++kc) {
    short8 b[NT];
#pragma unroll
    for (int nt = 0; nt < NT; ++nt)
      b[nt] = *reinterpret_cast<const short8*>(WT + (n0 + nt * 16 + l15) * K + kc * 32 + kg * 8);
#pragma unroll
    for (int m = 0; m < 2; ++m) {
      short8 a = *reinterpret_cast<const short8*>(A + (m * 16 + l15) * XSTRIDE + kc * 32 + kg * 8);
#pragma unroll
      for (int nt = 0; nt < NT; ++nt)
        acc[m][nt] = __builtin_amdgcn_mfma_f32_16x16x32_bf16(a, b[nt], acc[m][nt], 0, 0, 0);
    }
  }
}

#define ZERO_ACC(acc, NT)                                         \
  _Pragma("unroll") for (int m_ = 0; m_ < 2; ++m_)                \
  _Pragma("unroll") for (int n_ = 0; n_ < NT; ++n_)               \
    acc[m_][n_] = (f32x4){0.f, 0.f, 0.f, 0.f};

// ---- main fused kernel -------------------------------------------------
__global__ __launch_bounds__(256, 4) void fused_kernel(const float* __restrict__ x,
                                                       const u16* __restrict__ W,
                                                       const float* __restrict__ Pg,
                                                       float* __restrict__ out) {
  __shared__ __align__(16) u16 XA[ROWS * XSTRIDE];
  __shared__ __align__(16) u16 XB[ROWS * XSTRIDE];

  const int tid = threadIdx.x;
  const int row0 = blockIdx.x * ROWS;
  const int wv = tid >> 6, lane = tid & 63;
  const int kg = lane >> 4, l15 = lane & 15;

  // X load + input BN -> XA (bf16)
  {
    const float4* x4 = reinterpret_cast<const float4*>(x);
    const float4* s4 = reinterpret_cast<const float4*>(Pg + BN0S_P);
    const float4* t4 = reinterpret_cast<const float4*>(Pg + BN0T_P);
#pragma unroll
    for (int it = tid; it < ROWS * 64; it += 256) {
      int r = it >> 6, c4 = it & 63;
      float4 v = x4[(size_t)(row0 + r) * 64 + c4];
      float4 s = s4[c4];
      float4 t = t4[c4];
      short4v o;
      o[0] = (short)f2bf(v.x * s.x + t.x);
      o[1] = (short)f2bf(v.y * s.y + t.y);
      o[2] = (short)f2bf(v.z * s.z + t.z);
      o[3] = (short)f2bf(v.w * s.w + t.w);
      *reinterpret_cast<short4v*>(&XA[r * XSTRIDE + c4 * 4]) = o;
    }
  }
  __syncthreads();

  // ---- Q projection: q = xb @ qw + qb  (K=256, N=128) -> XB ----
  {
    f32x4 acc[2][2];
    ZERO_ACC(acc, 2)
    gemm_tile<256, 2>(XA, W + QWT_O, wv * 32, kg, l15, acc);
#pragma unroll
    for (int m = 0; m < 2; ++m)
#pragma unroll
      for (int nt = 0; nt < 2; ++nt)
#pragma unroll
        for (int i = 0; i < 4; ++i) {
          int col = wv * 32 + nt * 16 + l15;
          int row = m * 16 + kg * 4 + i;
          XB[row * XSTRIDE + col] = f2bf(acc[m][nt][i] + Pg[QB_P + col]);
        }
  }
  __syncthreads();

  // ---- per-row attention: head = wave (uniform -> s_load), row = lane<32 ----
  if (lane < ROWS) {
    const int h = wv;
    const int r = lane;
    float qv[32];
#pragma unroll
    for (int j = 0; j < 4; ++j) {
      short8 s = *reinterpret_cast<const short8*>(&XB[r * XSTRIDE + h * 32 + j * 8]);
#pragma unroll
      for (int e = 0; e < 8; ++e) qv[j * 8 + e] = bf2f((u16)s[e]);
    }
    float lp[8];
#pragma unroll
    for (int p = 0; p < 8; ++p) {
      float a = 0.f;
#pragma unroll
      for (int aa = 0; aa < 32; ++aa) a += qv[aa] * Pg[PK_P + h * 256 + p * 32 + aa];
      lp[p] = a * 0.17677669529663687f;  // 1/sqrt(32)
    }
    float mx = lp[0];
#pragma unroll
    for (int p = 1; p < 8; ++p) mx = fmaxf(mx, lp[p]);
    float se = 0.f;
#pragma unroll
    for (int p = 0; p < 8; ++p) se += expf(lp[p] - mx);
    float lse = mx + logf(se);
    float ent = 0.f;
#pragma unroll
    for (int p = 0; p < 8; ++p) { float t = lp[p] - lse; ent += expf(t) * t; }
    ent = -ent * 0.48089834696298783f;  // 1/ln(8)
    float sacc = 0.f;
#pragma unroll
    for (int t = 0; t < 32; ++t) {
      float hd = fmaxf(ent * Pg[TW1_P + h * 32 + t] + Pg[TB1_P + h * 32 + t], 0.f);
      sacc += hd * Pg[TW2_P + h * 32 + t];
    }
    float tau = 0.1f + 4.9f * sigmoidf_(sacc + Pg[TB2_P + h]);
    float itau = 1.f / tau;
    float at[8]; float s2 = 0.f;
#pragma unroll
    for (int p = 0; p < 8; ++p) { at[p] = expf((lp[p] - mx) * itau); s2 += at[p]; }
    float is2 = 1.f / s2;
    float ho[32];
#pragma unroll
    for (int aa = 0; aa < 32; ++aa) {
      float a = 0.f;
#pragma unroll
      for (int p = 0; p < 8; ++p) a += at[p] * Pg[PV_P + h * 256 + p * 32 + aa];
      ho[aa] = a * is2;
    }
    float h2[32]; float mu = 0.f;
#pragma unroll
    for (int e = 0; e < 32; ++e) {
      float a = Pg[OB_P + h * 32 + e];
#pragma unroll
      for (int aa = 0; aa < 32; ++aa) a += ho[aa] * Pg[OW_P + h * 1024 + aa * 32 + e];
      h2[e] = a; mu += a;
    }
    mu *= 0.03125f;
    float var = 0.f;
#pragma unroll
    for (int e = 0; e < 32; ++e) { float d = h2[e] - mu; var += d * d; }
    var *= 0.03125f;
    float rs = rsqrtf(var + 1e-5f);
#pragma unroll
    for (int e = 0; e < 32; ++e) {
      float v = (h2[e] - mu) * rs * Pg[LNG_P + h * 32 + e] + Pg[LNB_P + h * 32 + e];
      XB[r * XSTRIDE + h * 32 + e] = f2bf(v);
    }
  }
  __syncthreads();

  // ---- fuse: att_pre = comb @ fp_w + fp_b + xb  (K=128, N=256) -> XA ----
  {
    f32x4 acc[2][4];
    ZERO_ACC(acc, 4)
    gemm_tile<128, 4>(XB, W + FPT_O, wv * 64, kg, l15, acc);
#pragma unroll
    for (int m = 0; m < 2; ++m)
#pragma unroll
      for (int nt = 0; nt < 4; ++nt)
#pragma unroll
        for (int i = 0; i < 4; ++i) {
          int col = wv * 64 + nt * 16 + l15;
          int row = m * 16 + kg * 4 + i;
          float v = acc[m][nt][i] + Pg[FPB_P + col] + bf2f(XA[row * XSTRIDE + col]);
          XA[row * XSTRIDE + col] = f2bf(v);
        }
  }
  __syncthreads();
  // LayerNorm over 256 (8 threads per row)
  {
    int r = tid >> 3, oct = tid & 7;
    int base = r * XSTRIDE + oct * 32;
    float s = 0.f, s2 = 0.f;
#pragma unroll
    for (int j = 0; j < 4; ++j) {
      short8 v = *reinterpret_cast<const short8*>(&XA[base + j * 8]);
#pragma unroll
      for (int e = 0; e < 8; ++e) { float f = bf2f((u16)v[e]); s += f; s2 += f * f; }
    }
    s += __shfl_xor(s, 1);  s += __shfl_xor(s, 2);  s += __shfl_xor(s, 4);
    s2 += __shfl_xor(s2, 1); s2 += __shfl_xor(s2, 2); s2 += __shfl_xor(s2, 4);
    float mu = s * (1.f / 256.f);
    float var = s2 * (1.f / 256.f) - mu * mu;
    float rs = rsqrtf(var + 1e-5f);
#pragma unroll
    for (int j = 0; j < 4; ++j) {
      short8 v = *reinterpret_cast<const short8*>(&XA[base + j * 8]);
      short8 o;
#pragma unroll
      for (int e = 0; e < 8; ++e) {
        int col = oct * 32 + j * 8 + e;
        float f = (bf2f((u16)v[e]) - mu) * rs * Pg[FLNG_P + col] + Pg[FLNB_P + col];
        o[e] = (short)f2bf(f);
      }
      *reinterpret_cast<short8*>(&XA[base + j * 8]) = o;
    }
  }
  __syncthreads();

  // ---- SE1: s1 = relu(att @ se_w1 + b) (K=256, N=64) -> XB ----
  {
    f32x4 acc[2][1];
    ZERO_ACC(acc, 1)
    gemm_tile<256, 1>(XA, W + SE1T_O, wv * 16, kg, l15, acc);
#pragma unroll
    for (int m = 0; m < 2; ++m)
#pragma unroll
      for (int i = 0; i < 4; ++i) {
        int col = wv * 16 + l15;
        int row = m * 16 + kg * 4 + i;
        XB[row * XSTRIDE + col] = f2bf(fmaxf(acc[m][0][i] + Pg[SEB1_P + col], 0.f));
      }
  }
  __syncthreads();

  // ---- SE2 + gate: h = att * sigmoid(s1 @ se_w2 + b) (K=64, N=256) -> XA
  {
    f32x4 acc[2][4];
    ZERO_ACC(acc, 4)
    gemm_tile<64, 4>(XB, W + SE2T_O, wv * 64, kg, l15, acc);
#pragma unroll
    for (int m = 0; m < 2; ++m)
#pragma unroll
      for (int nt = 0; nt < 4; ++nt)
#pragma unroll
        for (int i = 0; i < 4; ++i) {
          int col = wv * 64 + nt * 16 + l15;
          int row = m * 16 + kg * 4 + i;
          float g = sigmoidf_(acc[m][nt][i] + Pg[SEB2_P + col]);
          float a = bf2f(XA[row * XSTRIDE + col]);
          XA[row * XSTRIDE + col] = f2bf(a * g);
        }
  }
  __syncthreads();

  // ---- block1: h = gelu(bn(h@W1)) + h (K=256, N=256) -> XB ----
  {
    f32x4 acc[2][4];
    ZERO_ACC(acc, 4)
    gemm_tile<256, 4>(XA, W + B1T_O, wv * 64, kg, l15, acc);
#pragma unroll
    for (int m = 0; m < 2; ++m)
#pragma unroll
      for (int nt = 0; nt < 4; ++nt)
#pragma unroll
        for (int i = 0; i < 4; ++i) {
          int col = wv * 64 + nt * 16 + l15;
          int row = m * 16 + kg * 4 + i;
          float y = Pg[B1S_P + col] * acc[m][nt][i] + Pg[B1TT_P + col];
          float g = gelu_exact(y);
          float h0 = bf2f(XA[row * XSTRIDE + col]);
          XB[row * XSTRIDE + col] = f2bf(g + h0);
        }
  }
  __syncthreads();

  // ---- block2: h = gelu(bn(h@W2)) + (h@R2 + b) (K=256, N=128 x2) -> XA ----
  {
    f32x4 acc[2][2], accr[2][2];
    ZERO_ACC(acc, 2)
    ZERO_ACC(accr, 2)
    gemm_tile<256, 2>(XB, W + B2T_O, wv * 32, kg, l15, acc);
    gemm_tile<256, 2>(XB, W + R2T_O, wv * 32, kg, l15, accr);
#pragma unroll
    for (int m = 0; m < 2; ++m)
#pragma unroll
      for (int nt = 0; nt < 2; ++nt)
#pragma unroll
        for (int i = 0; i < 4; ++i) {
          int col = wv * 32 + nt * 16 + l15;
          int row = m * 16 + kg * 4 + i;
          float y = Pg[B2S_P + col] * acc[m][nt][i] + Pg[B2TT_P + col];
          float g = gelu_exact(y);
          float y2 = accr[m][nt][i] + Pg[R2B_P + col];
          XA[row * XSTRIDE + col] = f2bf(g + y2);
        }
  }
  __syncthreads();

  // ---- block3: (K=128, N=64 x2) -> XB ----
  {
    f32x4 acc[2][1], accr[2][1];
    ZERO_ACC(acc, 1)
    ZERO_ACC(accr, 1)
    gemm_tile<128, 1>(XA, W + B3T_O, wv * 16, kg, l15, acc);
    gemm_tile<128, 1>(XA, W + R3T_O, wv * 16, kg, l15, accr);
#pragma unroll
    for (int m = 0; m < 2; ++m)
#pragma unroll
      for (int i = 0; i < 4; ++i) {
        int col = wv * 16 + l15;
        int row = m * 16 + kg * 4 + i;
        float y = Pg[B3S_P + col] * acc[m][0][i] + Pg[B3TT_P + col];
        float g = gelu_exact(y);
        float y2 = accr[m][0][i] + Pg[R3B_P + col];
        XB[row * XSTRIDE + col] = f2bf(g + y2);
      }
  }
  __syncthreads();

  // ---- c1: gelu(h@c1_w + b) (K=64, N=32); wave = (m-half, n-half) ----
  // wv>>1 selects row half (16 rows), wv&1 selects col half (16 cols).
  {
    const int mh = wv >> 1, nh = wv & 1;
    f32x4 ac = (f32x4){0.f, 0.f, 0.f, 0.f};
#pragma unroll
    for (int kc = 0; kc < 2; ++kc) {
      short8 b = *reinterpret_cast<const short8*>(W + C1T_O + (nh * 16 + l15) * 64 + kc * 32 + kg * 8);
      short8 a = *reinterpret_cast<const short8*>(&XB[(mh * 16 + l15) * XSTRIDE + kc * 32 + kg * 8]);
      ac = __builtin_amdgcn_mfma_f32_16x16x32_bf16(a, b, ac, 0, 0, 0);
    }
#pragma unroll
    for (int i = 0; i < 4; ++i) {
      int col = nh * 16 + l15;
      int row = mh * 16 + kg * 4 + i;
      float y = ac[i] + Pg[C1B_P + col];
      XB[row * XSTRIDE + 64 + col] = f2bf(gelu_exact(y));
    }
  }
  __syncthreads();

  // ---- c2 + sigmoid -> out ----
  if (tid < ROWS) {
    int r = tid;
    float s = Pg[C2B_P];
#pragma unroll
    for (int j = 0; j < 32; ++j) s += bf2f(XB[r * XSTRIDE + 64 + j]) * Pg[C2W_P + j];
    out[row0 + r] = sigmoidf_(s);
  }
}

// ---------------------------------------------------------------------------
extern "C" void kernel_launch(void* const* d_in, const int* in_sizes, int n_in,
                              void* d_out, int out_size, void* d_ws, size_t ws_size,
                              hipStream_t stream) {
  (void)in_sizes; (void)n_in; (void)out_size; (void)ws_size;
  Ptrs P;
  for (int i = 0; i < 51; ++i) P.p[i] = (const float*)d_in[i];

  u16* wsW = (u16*)d_ws;
  float* wsP = (float*)d_ws + WSP_F_OFF;

  prep_weights<<<256, 256, 0, stream>>>(P, wsW);
  prep_params<<<39, 256, 0, stream>>>(P, wsP);
  fused_kernel<<<65536 / ROWS, 256, 0, stream>>>((const float*)d_in[0], wsW, wsP, (float*)d_out);
}

// Round 7
// 380.043 us; speedup vs baseline: 1.4483x; 1.4483x over previous
//
#include <hip/hip_runtime.h>
#include <math.h>

// ---------------------------------------------------------------------------
// EDANet fused inference kernel, MI355X (gfx950).  Round 7.
// = Round 4 with the PVO input-index bug fixed:
//   PVO = pv @ ow  ->  pv is P.p[8], ow is P.p[13]   (r4 wrongly used p[7],p[8]
//   which are pk,pv -> absmax 4.7e-2 fail).
// All GEMM-shaped stages via mfma_f32_16x16x32_bf16 (fp32 accum); per-row
// scalar math on VALU.  32 rows/block, 4 blocks/CU target.
// ---------------------------------------------------------------------------

typedef unsigned short u16;
typedef __attribute__((ext_vector_type(8))) short short8;
typedef __attribute__((ext_vector_type(4))) short short4v;
typedef __attribute__((ext_vector_type(4))) float f32x4;

struct Ptrs { const float* p[51]; };

__device__ __host__ __forceinline__ u16 f2bf(float f) {
  union { float f; unsigned int i; } v; v.f = f;
  unsigned int u = v.i;
  unsigned int r = (u + 0x7fffu + ((u >> 16) & 1u)) >> 16;  // RNE
  return (u16)r;
}
__device__ __forceinline__ float bf2f(u16 u) {
  union { unsigned int i; float f; } v; v.i = ((unsigned int)u) << 16; return v.f;
}
__device__ __forceinline__ float gelu_exact(float y) {
  return 0.5f * y * (1.f + erff(y * 0.70710678118654752f));
}
__device__ __forceinline__ float sigmoidf_(float y) {
  return 1.f / (1.f + expf(-y));
}

// ---- workspace layout --------------------------------------------------
#define QWT_O   0         // [128][256]
#define FPT_O   32768     // [256][128]
#define SE1T_O  65536     // [64][256]
#define SE2T_O  81920     // [256][64]
#define B1T_O   98304     // [256][256]
#define B2T_O   163840    // [128][256]
#define R2T_O   196608    // [128][256]
#define B3T_O   229376    // [64][128]
#define R3T_O   237568    // [64][128]
#define C1T_O   245760    // [32][64]
#define W_TOTAL 247808
#define WSP_F_OFF 123904
// param blob float offsets
#define BN0S_P 0
#define BN0T_P 256
#define PK_P   512
#define PV_P   1536
#define OW_P   2560
#define TW1_P  6656
#define TB1_P  6784
#define TW2_P  6912
#define TB2_P  7040
#define OB_P   7044
#define LNG_P  7172
#define LNB_P  7300
#define QB_P   7428
#define FPB_P  7556
#define FLNG_P 7812
#define FLNB_P 8068
#define SEB1_P 8324
#define SEB2_P 8388
#define B1S_P  8644
#define B1TT_P 8900
#define B2S_P  9156
#define B2TT_P 9284
#define R2B_P  9412
#define B3S_P  9540
#define B3TT_P 9604
#define R3B_P  9668
#define C1B_P  9732
#define C2W_P  9764
#define C2B_P  9796
#define PVO_P  9800      // [H=4][P=8][A=32] = 1024 floats: pv @ ow per head
#define P_TOTAL 10824

#define XSTRIDE 264   // 256 + 8 bf16 pad (row stride 528B)
#define ROWS 32

// ---- prep: tiled transpose of weights to bf16 [out][in] ----------------
struct TDesc { int src; int K; int N; int dstOff; int isQW; };
struct TTab { TDesc d[10]; };

__global__ void prep_weights(Ptrs P, TTab T, u16* __restrict__ w) {
  __shared__ u16 tile[64][66];   // pad 66: conflict-free both phases
  int local = blockIdx.x;
  int mi = 0;
  for (; mi < 10; ++mi) {
    int cnt = (T.d[mi].K >> 6) * ((T.d[mi].N + 63) >> 6);
    if (local < cnt) break;
    local -= cnt;
  }
  TDesc d = T.d[mi];
  int ntN = (d.N + 63) >> 6;
  int tk = local / ntN, tn = local % ntN;
  int k0 = tk * 64, n0 = tn * 64;
  const float* __restrict__ src = P.p[d.src];
  int tid = threadIdx.x;
  int cc = tid & 63, rq = tid >> 6;
  // read src[k][n] coalesced over n
#pragma unroll
  for (int it = 0; it < 16; ++it) {
    int kk = it * 4 + rq;
    int n = n0 + cc, k = k0 + kk;
    float v = 0.f;
    if (n < d.N) {
      int si = d.isQW ? ((n >> 5) * 8192 + k * 32 + (n & 31))
                      : (k * d.N + n);
      v = src[si];
    }
    tile[kk][cc] = f2bf(v);
  }
  __syncthreads();
  // write w[dstOff + n*K + k] coalesced over k
#pragma unroll
  for (int it = 0; it < 16; ++it) {
    int rr = it * 4 + rq;
    int n = n0 + rr;
    if (n < d.N) w[d.dstOff + n * d.K + (k0 + cc)] = tile[cc][rr];
  }
}

// ---- prep: fp32 params (BN folded; PVO = pv @ ow per head) -------------
__global__ void prep_params(Ptrs P, float* __restrict__ wp) {
  int idx = blockIdx.x * blockDim.x + threadIdx.x;
  if (idx >= P_TOTAL) return;
  const float eps = 1e-5f;
  int i = idx; float v;
  if (i < 256)        { v = P.p[1][i] * rsqrtf(P.p[4][i] + eps); }
  else if (i < 512)   { int c = i - 256; float s = P.p[1][c] * rsqrtf(P.p[4][c] + eps); v = P.p[2][c] - P.p[3][c] * s; }
  else if (i < 1536)  v = P.p[7][i - 512];
  else if (i < 2560)  v = P.p[8][i - 1536];
  else if (i < 6656)  v = P.p[13][i - 2560];
  else if (i < 6784)  v = P.p[9][i - 6656];
  else if (i < 6912)  v = P.p[10][i - 6784];
  else if (i < 7040)  v = P.p[11][i - 6912];
  else if (i < 7044)  v = P.p[12][i - 7040];
  else if (i < 7172)  v = P.p[14][i - 7044];
  else if (i < 7300)  v = P.p[15][i - 7172];
  else if (i < 7428)  v = P.p[16][i - 7300];
  else if (i < 7556)  v = P.p[6][i - 7428];
  else if (i < 7812)  v = P.p[18][i - 7556];
  else if (i < 8068)  v = P.p[19][i - 7812];
  else if (i < 8324)  v = P.p[20][i - 8068];
  else if (i < 8388)  v = P.p[22][i - 8324];
  else if (i < 8644)  v = P.p[24][i - 8388];
  else if (i < 8900)  { int c = i - 8644; v = P.p[27][c] * rsqrtf(P.p[30][c] + eps); }
  else if (i < 9156)  { int c = i - 8900; float s = P.p[27][c] * rsqrtf(P.p[30][c] + eps); v = P.p[28][c] + (P.p[26][c] - P.p[29][c]) * s; }
  else if (i < 9284)  { int c = i - 9156; v = P.p[33][c] * rsqrtf(P.p[36][c] + eps); }
  else if (i < 9412)  { int c = i - 9284; float s = P.p[33][c] * rsqrtf(P.p[36][c] + eps); v = P.p[34][c] + (P.p[32][c] - P.p[35][c]) * s; }
  else if (i < 9540)  v = P.p[38][i - 9412];
  else if (i < 9604)  { int c = i - 9540; v = P.p[41][c] * rsqrtf(P.p[44][c] + eps); }
  else if (i < 9668)  { int c = i - 9604; float s = P.p[41][c] * rsqrtf(P.p[44][c] + eps); v = P.p[42][c] + (P.p[40][c] - P.p[43][c]) * s; }
  else if (i < 9732)  v = P.p[46][i - 9668];
  else if (i < 9764)  v = P.p[48][i - 9732];
  else if (i < 9796)  v = P.p[49][i - 9764];
  else if (i < 9797)  v = P.p[50][0];
  else if (i < 9800)  v = 0.f;
  else {
    // PVO[h][p][e] = sum_aa pv[h][p][aa] * ow[h][aa][e]
    // input order: p[7]=pk, p[8]=pv, p[13]=ow   (r4 bug: used p[7],p[8])
    int i2 = i - 9800;
    int h = i2 >> 8, p = (i2 >> 5) & 7, e = i2 & 31;
    const float* pv = P.p[8] + h * 256 + p * 32;
    const float* ow = P.p[13] + h * 1024 + e;
    float a = 0.f;
#pragma unroll
    for (int aa = 0; aa < 32; ++aa) a += pv[aa] * ow[aa * 32];
    v = a;
  }
  wp[idx] = v;
}

// ---- wave-level GEMM tile: 32 rows x (NT*16) cols, K from LDS ----------
template<int K, int NT>
__device__ __forceinline__ void gemm_tile(const u16* A, const u16* __restrict__ WT,
                                          int n0, int kg, int l15, f32x4 acc[2][NT]) {
#pragma unroll
  for (int kc = 0; kc < K / 32; ++kc) {
    short8 b[NT];
#pragma unroll
    for (int nt = 0; nt < NT; ++nt)
      b[nt] = *reinterpret_cast<const short8*>(WT + (n0 + nt * 16 + l15) * K + kc * 32 + kg * 8);
#pragma unroll
    for (int m = 0; m < 2; ++m) {
      short8 a = *reinterpret_cast<const short8*>(A + (m * 16 + l15) * XSTRIDE + kc * 32 + kg * 8);
#pragma unroll
      for (int nt = 0; nt < NT; ++nt)
        acc[m][nt] = __builtin_amdgcn_mfma_f32_16x16x32_bf16(a, b[nt], acc[m][nt], 0, 0, 0);
    }
  }
}

#define ZERO_ACC(acc, NT)                                         \
  _Pragma("unroll") for (int m_ = 0; m_ < 2; ++m_)                \
  _Pragma("unroll") for (int n_ = 0; n_ < NT; ++n_)               \
    acc[m_][n_] = (f32x4){0.f, 0.f, 0.f, 0.f};

// ---- main fused kernel -------------------------------------------------
__global__ __launch_bounds__(256, 4) void fused_kernel(const float* __restrict__ x,
                                                       const u16* __restrict__ W,
                                                       const float* __restrict__ Pg,
                                                       float* __restrict__ out) {
  __shared__ __align__(16) u16 XA[ROWS * XSTRIDE];
  __shared__ __align__(16) u16 XB[ROWS * XSTRIDE];

  const int tid = threadIdx.x;
  const int row0 = blockIdx.x * ROWS;
  const int wv = tid >> 6, lane = tid & 63;
  const int kg = lane >> 4, l15 = lane & 15;

  // X load + input BN -> XA (bf16)
  {
    const float4* x4 = reinterpret_cast<const float4*>(x);
    const float4* s4 = reinterpret_cast<const float4*>(Pg + BN0S_P);
    const float4* t4 = reinterpret_cast<const float4*>(Pg + BN0T_P);
#pragma unroll
    for (int it = tid; it < ROWS * 64; it += 256) {
      int r = it >> 6, c4 = it & 63;
      float4 v = x4[(size_t)(row0 + r) * 64 + c4];
      float4 s = s4[c4];
      float4 t = t4[c4];
      short4v o;
      o[0] = (short)f2bf(v.x * s.x + t.x);
      o[1] = (short)f2bf(v.y * s.y + t.y);
      o[2] = (short)f2bf(v.z * s.z + t.z);
      o[3] = (short)f2bf(v.w * s.w + t.w);
      *reinterpret_cast<short4v*>(&XA[r * XSTRIDE + c4 * 4]) = o;
    }
  }
  __syncthreads();

  // ---- Q projection: q = xb @ qw + qb  (K=256, N=128) -> XB ----
  {
    f32x4 acc[2][2];
    ZERO_ACC(acc, 2)
    gemm_tile<256, 2>(XA, W + QWT_O, wv * 32, kg, l15, acc);
#pragma unroll
    for (int m = 0; m < 2; ++m)
#pragma unroll
      for (int nt = 0; nt < 2; ++nt)
#pragma unroll
        for (int i = 0; i < 4; ++i) {
          int col = wv * 32 + nt * 16 + l15;
          int row = m * 16 + kg * 4 + i;
          XB[row * XSTRIDE + col] = f2bf(acc[m][nt][i] + Pg[QB_P + col]);
        }
  }
  __syncthreads();

  // ---- per-row attention: head = wave (uniform -> s_load), row = lane<32 ----
  if (lane < ROWS) {
    const int h = wv;
    const int r = lane;
    float lp[8];
    {
      float qv[32];
#pragma unroll
      for (int j = 0; j < 4; ++j) {
        short8 s = *reinterpret_cast<const short8*>(&XB[r * XSTRIDE + h * 32 + j * 8]);
#pragma unroll
        for (int e = 0; e < 8; ++e) qv[j * 8 + e] = bf2f((u16)s[e]);
      }
#pragma unroll
      for (int p = 0; p < 8; ++p) {
        float a = 0.f;
#pragma unroll
        for (int aa = 0; aa < 32; ++aa) a += qv[aa] * Pg[PK_P + h * 256 + p * 32 + aa];
        lp[p] = a * 0.17677669529663687f;  // 1/sqrt(32)
      }
    }
    float mx = lp[0];
#pragma unroll
    for (int p = 1; p < 8; ++p) mx = fmaxf(mx, lp[p]);
    float se = 0.f;
#pragma unroll
    for (int p = 0; p < 8; ++p) se += expf(lp[p] - mx);
    float lse = mx + logf(se);
    float ent = 0.f;
#pragma unroll
    for (int p = 0; p < 8; ++p) { float t = lp[p] - lse; ent += expf(t) * t; }
    ent = -ent * 0.48089834696298783f;  // 1/ln(8)
    float sacc = 0.f;
#pragma unroll
    for (int t = 0; t < 32; ++t) {
      float hd = fmaxf(ent * Pg[TW1_P + h * 32 + t] + Pg[TB1_P + h * 32 + t], 0.f);
      sacc += hd * Pg[TW2_P + h * 32 + t];
    }
    float tau = 0.1f + 4.9f * sigmoidf_(sacc + Pg[TB2_P + h]);
    float itau = 1.f / tau;
    float at[8]; float s2 = 0.f;
#pragma unroll
    for (int p = 0; p < 8; ++p) { at[p] = expf((lp[p] - mx) * itau); s2 += at[p]; }
    float is2 = 1.f / s2;
    // h2 = ob + is2 * (at @ PVO)   (PVO = pv @ ow, precomputed)
    float h2[32]; float mu = 0.f;
#pragma unroll
    for (int e = 0; e < 32; ++e) {
      float a = 0.f;
#pragma unroll
      for (int p = 0; p < 8; ++p) a += at[p] * Pg[PVO_P + h * 256 + p * 32 + e];
      a = a * is2 + Pg[OB_P + h * 32 + e];
      h2[e] = a; mu += a;
    }
    mu *= 0.03125f;
    float var = 0.f;
#pragma unroll
    for (int e = 0; e < 32; ++e) { float d = h2[e] - mu; var += d * d; }
    var *= 0.03125f;
    float rs = rsqrtf(var + 1e-5f);
#pragma unroll
    for (int e = 0; e < 32; ++e) {
      float v = (h2[e] - mu) * rs * Pg[LNG_P + h * 32 + e] + Pg[LNB_P + h * 32 + e];
      XB[r * XSTRIDE + h * 32 + e] = f2bf(v);
    }
  }
  __syncthreads();

  // ---- fuse: att_pre = comb @ fp_w + fp_b + xb  (K=128, N=256) -> XA ----
  {
    f32x4 acc[2][4];
    ZERO_ACC(acc, 4)
    gemm_tile<128, 4>(XB, W + FPT_O, wv * 64, kg, l15, acc);
#pragma unroll
    for (int m = 0; m < 2; ++m)
#pragma unroll
      for (int nt = 0; nt < 4; ++nt)
#pragma unroll
        for (int i = 0; i < 4; ++i) {
          int col = wv * 64 + nt * 16 + l15;
          int row = m * 16 + kg * 4 + i;
          float v = acc[m][nt][i] + Pg[FPB_P + col] + bf2f(XA[row * XSTRIDE + col]);
          XA[row * XSTRIDE + col] = f2bf(v);
        }
  }
  __syncthreads();
  // LayerNorm over 256 (8 threads per row)
  {
    int r = tid >> 3, oct = tid & 7;
    int base = r * XSTRIDE + oct * 32;
    float s = 0.f, s2 = 0.f;
#pragma unroll
    for (int j = 0; j < 4; ++j) {
      short8 v = *reinterpret_cast<const short8*>(&XA[base + j * 8]);
#pragma unroll
      for (int e = 0; e < 8; ++e) { float f = bf2f((u16)v[e]); s += f; s2 += f * f; }
    }
    s += __shfl_xor(s, 1);  s += __shfl_xor(s, 2);  s += __shfl_xor(s, 4);
    s2 += __shfl_xor(s2, 1); s2 += __shfl_xor(s2, 2); s2 += __shfl_xor(s2, 4);
    float mu = s * (1.f / 256.f);
    float var = s2 * (1.f / 256.f) - mu * mu;
    float rs = rsqrtf(var + 1e-5f);
#pragma unroll
    for (int j = 0; j < 4; ++j) {
      short8 v = *reinterpret_cast<const short8*>(&XA[base + j * 8]);
      short8 o;
#pragma unroll
      for (int e = 0; e < 8; ++e) {
        int col = oct * 32 + j * 8 + e;
        float f = (bf2f((u16)v[e]) - mu) * rs * Pg[FLNG_P + col] + Pg[FLNB_P + col];
        o[e] = (short)f2bf(f);
      }
      *reinterpret_cast<short8*>(&XA[base + j * 8]) = o;
    }
  }
  __syncthreads();

  // ---- SE1: s1 = relu(att @ se_w1 + b) (K=256, N=64) -> XB ----
  {
    f32x4 acc[2][1];
    ZERO_ACC(acc, 1)
    gemm_tile<256, 1>(XA, W + SE1T_O, wv * 16, kg, l15, acc);
#pragma unroll
    for (int m = 0; m < 2; ++m)
#pragma unroll
      for (int i = 0; i < 4; ++i) {
        int col = wv * 16 + l15;
        int row = m * 16 + kg * 4 + i;
        XB[row * XSTRIDE + col] = f2bf(fmaxf(acc[m][0][i] + Pg[SEB1_P + col], 0.f));
      }
  }
  __syncthreads();

  // ---- SE2 + gate: h = att * sigmoid(s1 @ se_w2 + b) (K=64, N=256) -> XA
  {
    f32x4 acc[2][4];
    ZERO_ACC(acc, 4)
    gemm_tile<64, 4>(XB, W + SE2T_O, wv * 64, kg, l15, acc);
#pragma unroll
    for (int m = 0; m < 2; ++m)
#pragma unroll
      for (int nt = 0; nt < 4; ++nt)
#pragma unroll
        for (int i = 0; i < 4; ++i) {
          int col = wv * 64 + nt * 16 + l15;
          int row = m * 16 + kg * 4 + i;
          float g = sigmoidf_(acc[m][nt][i] + Pg[SEB2_P + col]);
          float a = bf2f(XA[row * XSTRIDE + col]);
          XA[row * XSTRIDE + col] = f2bf(a * g);
        }
  }
  __syncthreads();

  // ---- block1: h = gelu(bn(h@W1)) + h (K=256, N=256) -> XB ----
  {
    f32x4 acc[2][4];
    ZERO_ACC(acc, 4)
    gemm_tile<256, 4>(XA, W + B1T_O, wv * 64, kg, l15, acc);
#pragma unroll
    for (int m = 0; m < 2; ++m)
#pragma unroll
      for (int nt = 0; nt < 4; ++nt)
#pragma unroll
        for (int i = 0; i < 4; ++i) {
          int col = wv * 64 + nt * 16 + l15;
          int row = m * 16 + kg * 4 + i;
          float y = Pg[B1S_P + col] * acc[m][nt][i] + Pg[B1TT_P + col];
          float g = gelu_exact(y);
          float h0 = bf2f(XA[row * XSTRIDE + col]);
          XB[row * XSTRIDE + col] = f2bf(g + h0);
        }
  }
  __syncthreads();

  // ---- block2: h = gelu(bn(h@W2)) + (h@R2 + b) (K=256, N=128 x2) -> XA ----
  {
    f32x4 acc[2][2], accr[2][2];
    ZERO_ACC(acc, 2)
    ZERO_ACC(accr, 2)
    gemm_tile<256, 2>(XB, W + B2T_O, wv * 32, kg, l15, acc);
    gemm_tile<256, 2>(XB, W + R2T_O, wv * 32, kg, l15, accr);
#pragma unroll
    for (int m = 0; m < 2; ++m)
#pragma unroll
      for (int nt = 0; nt < 2; ++nt)
#pragma unroll
        for (int i = 0; i < 4; ++i) {
          int col = wv * 32 + nt * 16 + l15;
          int row = m * 16 + kg * 4 + i;
          float y = Pg[B2S_P + col] * acc[m][nt][i] + Pg[B2TT_P + col];
          float g = gelu_exact(y);
          float y2 = accr[m][nt][i] + Pg[R2B_P + col];
          XA[row * XSTRIDE + col] = f2bf(g + y2);
        }
  }
  __syncthreads();

  // ---- block3: (K=128, N=64 x2) -> XB ----
  {
    f32x4 acc[2][1], accr[2][1];
    ZERO_ACC(acc, 1)
    ZERO_ACC(accr, 1)
    gemm_tile<128, 1>(XA, W + B3T_O, wv * 16, kg, l15, acc);
    gemm_tile<128, 1>(XA, W + R3T_O, wv * 16, kg, l15, accr);
#pragma unroll
    for (int m = 0; m < 2; ++m)
#pragma unroll
      for (int i = 0; i < 4; ++i) {
        int col = wv * 16 + l15;
        int row = m * 16 + kg * 4 + i;
        float y = Pg[B3S_P + col] * acc[m][0][i] + Pg[B3TT_P + col];
        float g = gelu_exact(y);
        float y2 = accr[m][0][i] + Pg[R3B_P + col];
        XB[row * XSTRIDE + col] = f2bf(g + y2);
      }
  }
  __syncthreads();

  // ---- c1: gelu(h@c1_w + b) (K=64, N=32); wave = (m-half, n-half) ----
  {
    const int mh = wv >> 1, nh = wv & 1;
    f32x4 ac = (f32x4){0.f, 0.f, 0.f, 0.f};
#pragma unroll
    for (int kc = 0; kc < 2; ++kc) {
      short8 b = *reinterpret_cast<const short8*>(W + C1T_O + (nh * 16 + l15) * 64 + kc * 32 + kg * 8);
      short8 a = *reinterpret_cast<const short8*>(&XB[(mh * 16 + l15) * XSTRIDE + kc * 32 + kg * 8]);
      ac = __builtin_amdgcn_mfma_f32_16x16x32_bf16(a, b, ac, 0, 0, 0);
    }
#pragma unroll
    for (int i = 0; i < 4; ++i) {
      int col = nh * 16 + l15;
      int row = mh * 16 + kg * 4 + i;
      float y = ac[i] + Pg[C1B_P + col];
      XB[row * XSTRIDE + 64 + col] = f2bf(gelu_exact(y));
    }
  }
  __syncthreads();

  // ---- c2 + sigmoid -> out ----
  if (tid < ROWS) {
    int r = tid;
    float s = Pg[C2B_P];
#pragma unroll
    for (int j = 0; j < 32; ++j) s += bf2f(XB[r * XSTRIDE + 64 + j]) * Pg[C2W_P + j];
    out[row0 + r] = sigmoidf_(s);
  }
}

// ---------------------------------------------------------------------------
extern "C" void kernel_launch(void* const* d_in, const int* in_sizes, int n_in,
                              void* d_out, int out_size, void* d_ws, size_t ws_size,
                              hipStream_t stream) {
  (void)in_sizes; (void)n_in; (void)out_size; (void)ws_size;
  Ptrs P;
  for (int i = 0; i < 51; ++i) P.p[i] = (const float*)d_in[i];

  u16* wsW = (u16*)d_ws;
  float* wsP = (float*)d_ws + WSP_F_OFF;

  // transpose descriptors: {src idx, K(in), N(out), dstOff, isQW}
  TTab T;
  T.d[0] = TDesc{ 5, 256, 128, QWT_O, 1};
  T.d[1] = TDesc{17, 128, 256, FPT_O, 0};
  T.d[2] = TDesc{21, 256,  64, SE1T_O, 0};
  T.d[3] = TDesc{23,  64, 256, SE2T_O, 0};
  T.d[4] = TDesc{25, 256, 256, B1T_O, 0};
  T.d[5] = TDesc{31, 256, 128, B2T_O, 0};
  T.d[6] = TDesc{37, 256, 128, R2T_O, 0};
  T.d[7] = TDesc{39, 128,  64, B3T_O, 0};
  T.d[8] = TDesc{45, 128,  64, R3T_O, 0};
  T.d[9] = TDesc{47,  64,  32, C1T_O, 0};
  int ntiles = 0;
  for (int i = 0; i < 10; ++i)
    ntiles += (T.d[i].K >> 6) * ((T.d[i].N + 63) >> 6);   // = 61

  prep_weights<<<ntiles, 256, 0, stream>>>(P, T, wsW);
  prep_params<<<(P_TOTAL + 255) / 256, 256, 0, stream>>>(P, wsP);
  fused_kernel<<<65536 / ROWS, 256, 0, stream>>>((const float*)d_in[0], wsW, wsP, (float*)d_out);
}